// Round 11
// baseline (38.895 us; speedup 1.0000x reference)
//
#include <hip/hip_runtime.h>
#include <math.h>
#include <limits.h>

#define BB 128
#define KK 2048
#define NN 4
#define CC 64
#define DD 3
#define SL 16           // K-slices per batch
#define KS (KK/SL)      // 128 k per slice
#define TCOST 128       // threads in crit_cost (= KS)
#define THREADS 256
#define LROW 65         // padded LDS row stride (bank-conflict-free column reads)

// ws layout (float words):
#define OFF_CVAL 0
#define OFF_CIDX (BB*SL*NN*NN)
#define OFF_OBJ  (2*BB*SL*NN*NN)

// ---- fast approximations: COST MATRIX ONLY (losses use accurate libm) ----
__device__ __forceinline__ float acospi_fast(float x) {
    // Hastings: acos(x) ~ sqrt(1-x)*p(x), abs err ~6.7e-5 rad; divided by pi.
    float ax = fabsf(x);
    float p = ((-0.0187293f*ax + 0.0742610f)*ax - 0.2121144f)*ax + 1.5707288f;
    float r = sqrtf(1.f - ax) * p;
    r = (x >= 0.f) ? r : 3.14159274f - r;
    return r * 0.31830988618379067f;
}

// ---------------- Kernel A: coalesced-staged cost + per-slice top-4 ----------------
// grid (SL, BB), block TCOST=128 (2 waves). cls tile streamed into LDS.
__global__ void __launch_bounds__(TCOST)
crit_cost(const float* __restrict__ loc_out, const float* __restrict__ obj_logit,
          const float* __restrict__ cls_logit, const float* __restrict__ gt_loc,
          const float* __restrict__ gt_cls, float* __restrict__ ws,
          float* __restrict__ out)
{
    __shared__ float zl[KS*LROW];      // 128 x 65 floats = 33.3 KB
    __shared__ float cost[NN][KS];     // 2 KB
    __shared__ float obj_s[2];

    const int sl  = blockIdx.x;
    const int b   = blockIdx.y;
    const int tid = threadIdx.x;
    const int w   = tid >> 6, lane = tid & 63;
    const int k   = sl*KS + tid;

    if (sl == 0 && b == 0 && tid == 0) out[0] = 0.f;   // zero accumulator for B

    // ---- issue primary loads early ----
    const float* lp = loc_out + ((size_t)b*KK + k)*DD;
    float l0 = lp[0], l1 = lp[1], l2 = lp[2];
    float x  = obj_logit[b*KK + k];

    // ---- stage the block's cls tile [KS][CC] into LDS, fully coalesced ----
    {
        const float4* zsrc = (const float4*)(cls_logit + (size_t)b*KK*CC + (size_t)sl*KS*CC);
        #pragma unroll
        for (int i = 0; i < (KS*CC/4)/TCOST; ++i) {      // 16 float4 per thread
            int f   = tid + TCOST*i;                      // float4 id in tile
            float4 v = zsrc[f];
            int row = f >> 4;                             // 16 float4 per row
            int c0  = (f & 15) << 2;
            float* d = &zl[row*LROW + c0];
            d[0] = v.x; d[1] = v.y; d[2] = v.z; d[3] = v.w;
        }
    }

    // ---- sync-free GT class setup: gt_cls is exact one-hot, CC == 64 lanes ----
    int   cls[NN]; float posin[NN];
    #pragma unroll
    for (int n = 0; n < NN; ++n) {
        float v = gt_cls[(b*NN+n)*CC + lane];
        unsigned long long m = __ballot(v > 0.5f);
        cls[n]   = __ffsll(m) - 1;
        posin[n] = 1.f / fmaxf((float)__popcll(m), 1.f);
    }

    // ---- gt vectors: uniform-address scalar loads ----
    float vt[NN][DD];
    #pragma unroll
    for (int n = 0; n < NN; ++n) {
        float g0 = gt_loc[(b*NN+n)*DD+0];
        float g1 = gt_loc[(b*NN+n)*DD+1];
        float g2 = gt_loc[(b*NN+n)*DD+2];
        float gin = 1.f / fmaxf(sqrtf(g0*g0 + g1*g1 + g2*g2), 1e-8f);
        vt[n][0] = g0*gin; vt[n][1] = g1*gin; vt[n][2] = g2*gin;
    }

    // ---- obj base + loc direction (overlaps with staging) ----
    float inv = 1.f / fmaxf(sqrtf(l0*l0 + l1*l1 + l2*l2), 1e-8f);
    float v0 = l0*inv, v1 = l1*inv, v2 = l2*inv;
    float obj_base = fmaxf(x, 0.f) + log1pf(expf(-fabsf(x)));   // LOSS: accurate
    float oc = -0.1f / (1.f + __expf(-x));                      // cost: fast

    float osum = obj_base;
    #pragma unroll
    for (int off = 32; off > 0; off >>= 1) osum += __shfl_xor(osum, off, 64);
    if (lane == 0) obj_s[w] = osum;

    __syncthreads();   // zl staged

    // ---- cost: z read from LDS (row stride 65 -> conflict-free columns) ----
    #pragma unroll
    for (int n = 0; n < NN; ++n) {
        float cosv = v0*vt[n][0] + v1*vt[n][1] + v2*vt[n][2];
        cosv = fminf(fmaxf(cosv, -1.f + 1e-6f), 1.f - 1e-6f);
        float loc_c = acospi_fast(cosv);
        float zz = zl[tid*LROW + cls[n]];
        float e  = __expf(-fabsf(zz));
        float lg = __logf(1.f + e);
        float sp = (zz >= 0.f) ? lg : (lg - zz);                // softplus(-z)
        float r1 = 1.f / (1.f + e);
        float sn = (zz >= 0.f) ? e*r1 : r1;                     // sigmoid(-z)
        float fp = 0.25f * sp * sn * sn;
        cost[n][tid] = loc_c + 0.25f*fp*posin[n] + oc;
    }
    __syncthreads();   // cost visible

    // ---- per-slice top-4: wave w handles rows {w, w+2} across KS=128 ----
    int* wsi = (int*)ws;
    for (int rr = w; rr < NN; rr += 2) {
        float vv[2]; int gi[2];
        #pragma unroll
        for (int j = 0; j < 2; ++j) {
            vv[j] = cost[rr][lane + 64*j];
            gi[j] = sl*KS + lane + 64*j;
        }
        float cr_val[NN]; int cr_idx[NN];
        #pragma unroll
        for (int r = 0; r < 4; ++r) {
            float bv = vv[0]; int bi = gi[0];
            if (vv[1] < bv || (vv[1] == bv && gi[1] < bi)) { bv = vv[1]; bi = gi[1]; }
            #pragma unroll
            for (int off = 32; off > 0; off >>= 1) {
                float ov = __shfl_xor(bv, off, 64);
                int   oi = __shfl_xor(bi, off, 64);
                if (ov < bv || (ov == bv && oi < bi)) { bv = ov; bi = oi; }
            }
            cr_val[r] = bv; cr_idx[r] = bi;
            if (gi[0] == bi) vv[0] = INFINITY;
            if (gi[1] == bi) vv[1] = INFINITY;
        }
        if (lane == 0) {
            int base = ((b*SL + sl)*NN + rr)*NN;
            #pragma unroll
            for (int r = 0; r < NN; ++r) {
                ws[OFF_CVAL + base + r]  = cr_val[r];
                wsi[OFF_CIDX + base + r] = cr_idx[r];
            }
        }
    }
    if (tid == 0)
        ws[OFF_OBJ + b*SL + sl] = obj_s[0] + obj_s[1];
}

// ------- Kernel B: merge candidates, assign, weighted loss -> one atomicAdd -------
__global__ void __launch_bounds__(THREADS)
crit_match(const float* __restrict__ loc_out, const float* __restrict__ obj_logit,
           const float* __restrict__ cls_logit, const float* __restrict__ gt_loc,
           const float* __restrict__ gt_cls, float* __restrict__ ws,
           float* __restrict__ out)
{
    __shared__ float cand_val[NN][NN];
    __shared__ int   cand_idx[NN][NN];
    __shared__ int   s_pred[NN];
    __shared__ float s_best[4];
    __shared__ int   s_bestc[4];
    __shared__ float red[4];
    __shared__ float s_lo;      // weighted loc+obj contribution

    const int b = blockIdx.x, tid = threadIdx.x;
    const int w = tid >> 6, lane = tid & 63;
    const int* wsi = (const int*)ws;

    // Merge: wave w holds the SL*NN = 64 candidates of row w, one per lane.
    {
        int sl = lane >> 2, r = lane & 3;
        int base = ((b*SL + sl)*NN + w)*NN + r;
        float v = ws[OFF_CVAL + base];
        int idx = wsi[OFF_CIDX + base];
        #pragma unroll
        for (int r2 = 0; r2 < NN; ++r2) {
            float bv = v; int bi = idx;
            #pragma unroll
            for (int off = 32; off > 0; off >>= 1) {
                float ov = __shfl_xor(bv, off, 64);
                int   oi = __shfl_xor(bi, off, 64);
                if (ov < bv || (ov == bv && oi < bi)) { bv = ov; bi = oi; }
            }
            if (lane == 0) { cand_val[w][r2] = bv; cand_idx[w][r2] = bi; }
            if (idx == bi) v = INFINITY;   // mask winner
        }
    }
    __syncthreads();

    // Brute force: thread tid evaluates combo tid (a0..a3 = 2-bit fields).
    {
        int a0 = (tid >> 6) & 3, a1 = (tid >> 4) & 3, a2 = (tid >> 2) & 3, a3 = tid & 3;
        int c0 = cand_idx[0][a0], c1 = cand_idx[1][a1];
        int c2 = cand_idx[2][a2], c3 = cand_idx[3][a3];
        bool valid = (c0!=c1) & (c0!=c2) & (c0!=c3) & (c1!=c2) & (c1!=c3) & (c2!=c3);
        float t = cand_val[0][a0] + cand_val[1][a1] + cand_val[2][a2] + cand_val[3][a3];
        float bv = valid ? t : INFINITY;
        int   bc = tid;
        #pragma unroll
        for (int off = 32; off > 0; off >>= 1) {
            float ov = __shfl_xor(bv, off, 64);
            int   oc = __shfl_xor(bc, off, 64);
            if (ov < bv || (ov == bv && oc < bc)) { bv = ov; bc = oc; }
        }
        if (lane == 0) { s_best[w] = bv; s_bestc[w] = bc; }
    }
    __syncthreads();

    if (tid == 0) {
        float bv = s_best[0]; int bc = s_bestc[0];
        for (int i = 1; i < 4; ++i)
            if (s_best[i] < bv || (s_best[i] == bv && s_bestc[i] < bc)) { bv = s_best[i]; bc = s_bestc[i]; }
        int a0 = (bc >> 6) & 3, a1 = (bc >> 4) & 3, a2 = (bc >> 2) & 3, a3 = bc & 3;
        s_pred[0] = cand_idx[0][a0]; s_pred[1] = cand_idx[1][a1];
        s_pred[2] = cand_idx[2][a2]; s_pred[3] = cand_idx[3][a3];

        // obj partial (accurate)
        float om = 0.f;
        for (int sl = 0; sl < SL; ++sl) om += ws[OFF_OBJ + b*SL + sl];
        for (int n = 0; n < NN; ++n) om -= obj_logit[b*KK + s_pred[n]];

        // loc partial (12 terms)
        float s = 0.f;
        for (int n = 0; n < NN; ++n)
            for (int d = 0; d < DD; ++d) {
                float diff = loc_out[((size_t)b*KK + s_pred[n])*DD + d] - gt_loc[(b*NN+n)*DD + d];
                s += diff*diff;
            }
        s_lo = s / (float)(BB*NN*DD) + om / (float)(BB*KK);
    }
    __syncthreads();

    // cls partial: 256 threads = 4 rows x 64 classes; accurate focal BCE.
    {
        int n = w, c = lane;
        float zz = cls_logit[((size_t)b*KK + s_pred[n])*CC + c];
        float tgt = gt_cls[(b*NN+n)*CC + c];
        float p  = 1.f / (1.f + expf(-zz));
        float ce = fmaxf(zz, 0.f) - zz*tgt + log1pf(expf(-fabsf(zz)));
        float pt = p*tgt + (1.f-p)*(1.f-tgt);
        float at = 0.25f*tgt + 0.75f*(1.f-tgt);
        float om1 = 1.f - pt;
        float r = at * ce * om1 * om1;
        #pragma unroll
        for (int off = 32; off > 0; off >>= 1) r += __shfl_xor(r, off, 64);
        if (lane == 0) red[n] = r;
    }
    __syncthreads();

    // One relaxed float atomic per block: fully-weighted batch contribution.
    if (tid == 0) {
        float total = s_lo + (red[0] + red[1] + red[2] + red[3]) / (float)(BB*NN*CC);
        atomicAdd(out, total);
    }
}

extern "C" void kernel_launch(void* const* d_in, const int* in_sizes, int n_in,
                              void* d_out, int out_size, void* d_ws, size_t ws_size,
                              hipStream_t stream) {
    const float* loc_out   = (const float*)d_in[0];
    const float* obj_logit = (const float*)d_in[1];
    const float* cls_logit = (const float*)d_in[2];
    const float* gt_loc    = (const float*)d_in[3];
    const float* gt_cls    = (const float*)d_in[4];
    float* ws  = (float*)d_ws;
    float* out = (float*)d_out;

    hipLaunchKernelGGL(crit_cost, dim3(SL, BB), dim3(TCOST), 0, stream,
                       loc_out, obj_logit, cls_logit, gt_loc, gt_cls, ws, out);
    hipLaunchKernelGGL(crit_match, dim3(BB), dim3(THREADS), 0, stream,
                       loc_out, obj_logit, cls_logit, gt_loc, gt_cls, ws, out);
}

// Round 12
// 28.108 us; speedup vs baseline: 1.3838x; 1.3838x over previous
//
#include <hip/hip_runtime.h>
#include <math.h>
#include <limits.h>

#define BB 128
#define KK 2048
#define NN 4
#define CC 64
#define DD 3
#define SL 4            // K-slices per batch
#define KS (KK/SL)      // 512 k per slice
#define TCOST 256       // threads in crit_cost (4 waves); 2 k per thread
#define KPT 2
#define THREADS 256

// ws layout (float words):
#define OFF_CVAL 0
#define OFF_CIDX (BB*SL*NN*NN)
#define OFF_OBJ  (2*BB*SL*NN*NN)

// ---- fast approximations: COST MATRIX ONLY (losses use accurate libm) ----
__device__ __forceinline__ float acospi_fast(float x) {
    // Hastings: acos(x) ~ sqrt(1-x)*p(x), abs err ~6.7e-5 rad; divided by pi.
    float ax = fabsf(x);
    float p = ((-0.0187293f*ax + 0.0742610f)*ax - 0.2121144f)*ax + 1.5707288f;
    float r = sqrtf(1.f - ax) * p;
    r = (x >= 0.f) ? r : 3.14159274f - r;
    return r * 0.31830988618379067f;
}

// ---------------- Kernel A: cost + per-slice top-4 per GT row ----------------
// grid (SL, BB) = 512 blocks x 256 threads; 2 k's per thread; top-4 over 512/wave.
__global__ void __launch_bounds__(TCOST)
crit_cost(const float* __restrict__ loc_out, const float* __restrict__ obj_logit,
          const float* __restrict__ cls_logit, const float* __restrict__ gt_loc,
          const float* __restrict__ gt_cls, float* __restrict__ ws,
          float* __restrict__ out)
{
    __shared__ float cost[NN][KS];     // 8 KB
    __shared__ float obj_s[4];

    const int sl  = blockIdx.x;
    const int b   = blockIdx.y;
    const int tid = threadIdx.x;
    const int w   = tid >> 6, lane = tid & 63;

    if (sl == 0 && b == 0 && tid == 0) out[0] = 0.f;   // zero accumulator for B

    // ---- issue primary loads early (2 k's per thread) ----
    const int k0 = sl*KS + tid, k1 = k0 + TCOST;
    const float* lp0 = loc_out + ((size_t)b*KK + k0)*DD;
    const float* lp1 = loc_out + ((size_t)b*KK + k1)*DD;
    float a0 = lp0[0], a1 = lp0[1], a2 = lp0[2];
    float b0 = lp1[0], b1 = lp1[1], b2 = lp1[2];
    float x0 = obj_logit[b*KK + k0];
    float x1 = obj_logit[b*KK + k1];

    // ---- sync-free GT class setup: gt_cls is exact one-hot, CC == 64 lanes ----
    int   cls[NN]; float posin[NN];
    #pragma unroll
    for (int n = 0; n < NN; ++n) {
        float v = gt_cls[(b*NN+n)*CC + lane];
        unsigned long long m = __ballot(v > 0.5f);
        cls[n]   = __ffsll(m) - 1;
        posin[n] = 1.f / fmaxf((float)__popcll(m), 1.f);
    }

    // ---- issue the 8 strided cls gathers ASAP ----
    float z0[NN], z1[NN];
    #pragma unroll
    for (int n = 0; n < NN; ++n) {
        z0[n] = cls_logit[((size_t)b*KK + k0)*CC + cls[n]];
        z1[n] = cls_logit[((size_t)b*KK + k1)*CC + cls[n]];
    }

    // ---- gt vectors: uniform-address scalar loads ----
    float vt[NN][DD];
    #pragma unroll
    for (int n = 0; n < NN; ++n) {
        float g0 = gt_loc[(b*NN+n)*DD+0];
        float g1 = gt_loc[(b*NN+n)*DD+1];
        float g2 = gt_loc[(b*NN+n)*DD+2];
        float gin = 1.f / fmaxf(sqrtf(g0*g0 + g1*g1 + g2*g2), 1e-8f);
        vt[n][0] = g0*gin; vt[n][1] = g1*gin; vt[n][2] = g2*gin;
    }

    // ---- math for both k's (overlaps with in-flight gathers) ----
    float inva = 1.f / fmaxf(sqrtf(a0*a0 + a1*a1 + a2*a2), 1e-8f);
    float invb = 1.f / fmaxf(sqrtf(b0*b0 + b1*b1 + b2*b2), 1e-8f);
    float u0 = a0*inva, u1 = a1*inva, u2 = a2*inva;
    float q0 = b0*invb, q1 = b1*invb, q2 = b2*invb;
    float obj_base = fmaxf(x0, 0.f) + log1pf(expf(-fabsf(x0)))
                   + fmaxf(x1, 0.f) + log1pf(expf(-fabsf(x1)));  // LOSS: accurate
    float oc0 = -0.1f / (1.f + __expf(-x0));                     // cost: fast
    float oc1 = -0.1f / (1.f + __expf(-x1));
    #pragma unroll
    for (int n = 0; n < NN; ++n) {
        float ca = u0*vt[n][0] + u1*vt[n][1] + u2*vt[n][2];
        float cb = q0*vt[n][0] + q1*vt[n][1] + q2*vt[n][2];
        ca = fminf(fmaxf(ca, -1.f + 1e-6f), 1.f - 1e-6f);
        cb = fminf(fmaxf(cb, -1.f + 1e-6f), 1.f - 1e-6f);
        float za = z0[n], zb = z1[n];
        float ea  = __expf(-fabsf(za)),        eb  = __expf(-fabsf(zb));
        float la  = __logf(1.f + ea),          lb  = __logf(1.f + eb);
        float spa = (za >= 0.f) ? la : (la - za);
        float spb = (zb >= 0.f) ? lb : (lb - zb);
        float ra  = 1.f / (1.f + ea),          rb  = 1.f / (1.f + eb);
        float sa  = (za >= 0.f) ? ea*ra : ra,  sb  = (zb >= 0.f) ? eb*rb : rb;
        cost[n][tid]       = acospi_fast(ca) + 0.25f*(0.25f*spa*sa*sa)*posin[n] + oc0;
        cost[n][tid+TCOST] = acospi_fast(cb) + 0.25f*(0.25f*spb*sb*sb)*posin[n] + oc1;
    }

    // obj partial: wave shfl-sum, 4-wave combine.
    float osum = obj_base;
    #pragma unroll
    for (int off = 32; off > 0; off >>= 1) osum += __shfl_xor(osum, off, 64);
    if (lane == 0) obj_s[w] = osum;
    __syncthreads();   // cost[][] + obj_s visible

    // ---- per-slice top-4 of row w: 512 values, 8 per lane ----
    float vv[8]; int gi[8];
    #pragma unroll
    for (int j = 0; j < 8; ++j) {
        vv[j] = cost[w][lane + 64*j];
        gi[j] = sl*KS + lane + 64*j;
    }
    float cr_val[NN]; int cr_idx[NN];
    #pragma unroll
    for (int r = 0; r < NN; ++r) {
        // local argmin over 8 (tree)
        float bv = vv[0]; int bi = gi[0];
        #pragma unroll
        for (int j = 1; j < 8; ++j)
            if (vv[j] < bv || (vv[j] == bv && gi[j] < bi)) { bv = vv[j]; bi = gi[j]; }
        // wave all-reduce argmin
        #pragma unroll
        for (int off = 32; off > 0; off >>= 1) {
            float ov = __shfl_xor(bv, off, 64);
            int   oi = __shfl_xor(bi, off, 64);
            if (ov < bv || (ov == bv && oi < bi)) { bv = ov; bi = oi; }
        }
        cr_val[r] = bv; cr_idx[r] = bi;
        #pragma unroll
        for (int j = 0; j < 8; ++j) if (gi[j] == bi) vv[j] = INFINITY;
    }
    if (lane == 0) {
        int base = ((b*SL + sl)*NN + w)*NN;
        int* wsi = (int*)ws;
        #pragma unroll
        for (int r = 0; r < NN; ++r) {
            ws[OFF_CVAL + base + r]  = cr_val[r];
            wsi[OFF_CIDX + base + r] = cr_idx[r];
        }
    }
    if (tid == 0)
        ws[OFF_OBJ + b*SL + sl] = obj_s[0] + obj_s[1] + obj_s[2] + obj_s[3];
}

// ------- Kernel B: merge candidates, assign, weighted loss -> one atomicAdd -------
__global__ void __launch_bounds__(THREADS)
crit_match(const float* __restrict__ loc_out, const float* __restrict__ obj_logit,
           const float* __restrict__ cls_logit, const float* __restrict__ gt_loc,
           const float* __restrict__ gt_cls, float* __restrict__ ws,
           float* __restrict__ out)
{
    __shared__ float cand_val[NN][NN];
    __shared__ int   cand_idx[NN][NN];
    __shared__ int   s_pred[NN];
    __shared__ float s_best[4];
    __shared__ int   s_bestc[4];
    __shared__ float red[4];
    __shared__ float s_lo;      // weighted loc+obj contribution

    const int b = blockIdx.x, tid = threadIdx.x;
    const int w = tid >> 6, lane = tid & 63;
    const int* wsi = (const int*)ws;

    // Merge: wave w holds the SL*NN = 16 candidates of row w in lanes 0..15.
    {
        float v = INFINITY; int idx = INT_MAX;
        if (lane < SL*NN) {
            int sl = lane >> 2, r = lane & 3;
            int base = ((b*SL + sl)*NN + w)*NN + r;
            v   = ws[OFF_CVAL + base];
            idx = wsi[OFF_CIDX + base];
        }
        #pragma unroll
        for (int r2 = 0; r2 < NN; ++r2) {
            float bv = v; int bi = idx;
            #pragma unroll
            for (int off = 32; off > 0; off >>= 1) {
                float ov = __shfl_xor(bv, off, 64);
                int   oi = __shfl_xor(bi, off, 64);
                if (ov < bv || (ov == bv && oi < bi)) { bv = ov; bi = oi; }
            }
            if (lane == 0) { cand_val[w][r2] = bv; cand_idx[w][r2] = bi; }
            if (idx == bi) v = INFINITY;   // mask winner
        }
    }
    __syncthreads();

    // Brute force: thread tid evaluates combo tid (a0..a3 = 2-bit fields).
    {
        int a0 = (tid >> 6) & 3, a1 = (tid >> 4) & 3, a2 = (tid >> 2) & 3, a3 = tid & 3;
        int c0 = cand_idx[0][a0], c1 = cand_idx[1][a1];
        int c2 = cand_idx[2][a2], c3 = cand_idx[3][a3];
        bool valid = (c0!=c1) & (c0!=c2) & (c0!=c3) & (c1!=c2) & (c1!=c3) & (c2!=c3);
        float t = cand_val[0][a0] + cand_val[1][a1] + cand_val[2][a2] + cand_val[3][a3];
        float bv = valid ? t : INFINITY;
        int   bc = tid;
        #pragma unroll
        for (int off = 32; off > 0; off >>= 1) {
            float ov = __shfl_xor(bv, off, 64);
            int   oc = __shfl_xor(bc, off, 64);
            if (ov < bv || (ov == bv && oc < bc)) { bv = ov; bc = oc; }
        }
        if (lane == 0) { s_best[w] = bv; s_bestc[w] = bc; }
    }
    __syncthreads();

    if (tid == 0) {
        float bv = s_best[0]; int bc = s_bestc[0];
        for (int i = 1; i < 4; ++i)
            if (s_best[i] < bv || (s_best[i] == bv && s_bestc[i] < bc)) { bv = s_best[i]; bc = s_bestc[i]; }
        int a0 = (bc >> 6) & 3, a1 = (bc >> 4) & 3, a2 = (bc >> 2) & 3, a3 = bc & 3;
        s_pred[0] = cand_idx[0][a0]; s_pred[1] = cand_idx[1][a1];
        s_pred[2] = cand_idx[2][a2]; s_pred[3] = cand_idx[3][a3];

        // obj partial (accurate)
        float om = 0.f;
        for (int sl = 0; sl < SL; ++sl) om += ws[OFF_OBJ + b*SL + sl];
        for (int n = 0; n < NN; ++n) om -= obj_logit[b*KK + s_pred[n]];

        // loc partial (12 terms)
        float s = 0.f;
        for (int n = 0; n < NN; ++n)
            for (int d = 0; d < DD; ++d) {
                float diff = loc_out[((size_t)b*KK + s_pred[n])*DD + d] - gt_loc[(b*NN+n)*DD + d];
                s += diff*diff;
            }
        s_lo = s / (float)(BB*NN*DD) + om / (float)(BB*KK);
    }
    __syncthreads();

    // cls partial: 256 threads = 4 rows x 64 classes; accurate focal BCE.
    {
        int n = w, c = lane;
        float zz = cls_logit[((size_t)b*KK + s_pred[n])*CC + c];
        float tgt = gt_cls[(b*NN+n)*CC + c];
        float p  = 1.f / (1.f + expf(-zz));
        float ce = fmaxf(zz, 0.f) - zz*tgt + log1pf(expf(-fabsf(zz)));
        float pt = p*tgt + (1.f-p)*(1.f-tgt);
        float at = 0.25f*tgt + 0.75f*(1.f-tgt);
        float om1 = 1.f - pt;
        float r = at * ce * om1 * om1;
        #pragma unroll
        for (int off = 32; off > 0; off >>= 1) r += __shfl_xor(r, off, 64);
        if (lane == 0) red[n] = r;
    }
    __syncthreads();

    // One relaxed float atomic per block: fully-weighted batch contribution.
    if (tid == 0) {
        float total = s_lo + (red[0] + red[1] + red[2] + red[3]) / (float)(BB*NN*CC);
        atomicAdd(out, total);
    }
}

extern "C" void kernel_launch(void* const* d_in, const int* in_sizes, int n_in,
                              void* d_out, int out_size, void* d_ws, size_t ws_size,
                              hipStream_t stream) {
    const float* loc_out   = (const float*)d_in[0];
    const float* obj_logit = (const float*)d_in[1];
    const float* cls_logit = (const float*)d_in[2];
    const float* gt_loc    = (const float*)d_in[3];
    const float* gt_cls    = (const float*)d_in[4];
    float* ws  = (float*)d_ws;
    float* out = (float*)d_out;

    hipLaunchKernelGGL(crit_cost, dim3(SL, BB), dim3(TCOST), 0, stream,
                       loc_out, obj_logit, cls_logit, gt_loc, gt_cls, ws, out);
    hipLaunchKernelGGL(crit_match, dim3(BB), dim3(THREADS), 0, stream,
                       loc_out, obj_logit, cls_logit, gt_loc, gt_cls, ws, out);
}

// Round 14
// 27.662 us; speedup vs baseline: 1.4061x; 1.0161x over previous
//
#include <hip/hip_runtime.h>
#include <math.h>
#include <limits.h>

#define BB 128
#define KK 2048
#define NN 4
#define CC 64
#define DD 3
#define SL 8            // K-slices per batch
#define KS (KK/SL)      // 256 k per slice
#define THREADS 256

// ws layout (float words):
#define OFF_CVAL 0
#define OFF_CIDX (BB*SL*NN*NN)
#define OFF_OBJ  (2*BB*SL*NN*NN)

// ---- fast approximations: COST MATRIX ONLY (losses use accurate libm) ----
__device__ __forceinline__ float acospi_fast(float x) {
    // Hastings: acos(x) ~ sqrt(1-x)*p(x), abs err ~6.7e-5 rad; divided by pi.
    float ax = fabsf(x);
    float p = ((-0.0187293f*ax + 0.0742610f)*ax - 0.2121144f)*ax + 1.5707288f;
    float r = sqrtf(1.f - ax) * p;
    r = (x >= 0.f) ? r : 3.14159274f - r;
    return r * 0.31830988618379067f;
}

// ---------------- Kernel A: cost + per-slice top-4 per GT row ----------------
__global__ void __launch_bounds__(THREADS)
crit_cost(const float* __restrict__ loc_out, const float* __restrict__ obj_logit,
          const float* __restrict__ cls_logit, const float* __restrict__ gt_loc,
          const float* __restrict__ gt_cls, float* __restrict__ ws,
          float* __restrict__ out)
{
    __shared__ float cost[NN][KS];     // 4 KB
    __shared__ float obj_s[4];

    const int sl  = blockIdx.x;
    const int b   = blockIdx.y;
    const int tid = threadIdx.x;
    const int w   = tid >> 6, lane = tid & 63;
    const int k   = sl*KS + tid;

    if (sl == 0 && b == 0 && tid == 0) out[0] = 0.f;   // zero accumulator for B

    // ---- CRITICAL CHAIN HEAD: gt_cls loads first (z-gather addresses depend
    //      on them via ballot). loc/obj loads fill the shadow below. ----
    float gv[NN];
    #pragma unroll
    for (int n = 0; n < NN; ++n) gv[n] = gt_cls[(b*NN+n)*CC + lane];

    // ---- independent loads issued into the gt_cls shadow ----
    const float* lp = loc_out + ((size_t)b*KK + k)*DD;
    float l0 = lp[0], l1 = lp[1], l2 = lp[2];
    float x  = obj_logit[b*KK + k];

    // ---- ballots -> class indices; then z-gathers ASAP ----
    int   cls[NN]; float posin[NN];
    #pragma unroll
    for (int n = 0; n < NN; ++n) {
        unsigned long long m = __ballot(gv[n] > 0.5f);
        cls[n]   = __ffsll(m) - 1;
        posin[n] = 1.f / fmaxf((float)__popcll(m), 1.f);
    }
    float z[NN];
    #pragma unroll
    for (int n = 0; n < NN; ++n)
        z[n] = cls_logit[((size_t)b*KK + k)*CC + cls[n]];

    // ---- gt vectors: uniform-address scalar loads ----
    float vt[NN][DD];
    #pragma unroll
    for (int n = 0; n < NN; ++n) {
        float g0 = gt_loc[(b*NN+n)*DD+0];
        float g1 = gt_loc[(b*NN+n)*DD+1];
        float g2 = gt_loc[(b*NN+n)*DD+2];
        float gin = 1.f / fmaxf(sqrtf(g0*g0 + g1*g1 + g2*g2), 1e-8f);
        vt[n][0] = g0*gin; vt[n][1] = g1*gin; vt[n][2] = g2*gin;
    }

    // ---- math (overlaps with in-flight gathers) ----
    float inv = 1.f / fmaxf(sqrtf(l0*l0 + l1*l1 + l2*l2), 1e-8f);
    float v0 = l0*inv, v1 = l1*inv, v2 = l2*inv;
    float obj_base = fmaxf(x, 0.f) + log1pf(expf(-fabsf(x)));   // LOSS: accurate
    float oc = -0.1f / (1.f + __expf(-x));                      // cost: fast
    #pragma unroll
    for (int n = 0; n < NN; ++n) {
        float cosv = v0*vt[n][0] + v1*vt[n][1] + v2*vt[n][2];
        cosv = fminf(fmaxf(cosv, -1.f + 1e-6f), 1.f - 1e-6f);
        float loc_c = acospi_fast(cosv);
        float zz = z[n];
        float e  = __expf(-fabsf(zz));
        float lg = __logf(1.f + e);
        float sp = (zz >= 0.f) ? lg : (lg - zz);                // softplus(-z)
        float r1 = 1.f / (1.f + e);
        float sn = (zz >= 0.f) ? e*r1 : r1;                     // sigmoid(-z)
        float fp = 0.25f * sp * sn * sn;
        cost[n][tid] = loc_c + 0.25f*fp*posin[n] + oc;
    }

    // obj partial: wave shfl-sum, 4-wave combine.
    float osum = obj_base;
    #pragma unroll
    for (int off = 32; off > 0; off >>= 1) osum += __shfl_xor(osum, off, 64);
    if (lane == 0) obj_s[w] = osum;
    __syncthreads();   // cost[][] + obj_s visible

    // ---- per-slice top-4 of row w (wave-synchronous) ----
    float vv[4]; int gi[4];
    #pragma unroll
    for (int j = 0; j < 4; ++j) {
        vv[j] = cost[w][lane + 64*j];
        gi[j] = sl*KS + lane + 64*j;
    }
    float cr_val[NN]; int cr_idx[NN];
    #pragma unroll
    for (int r = 0; r < NN; ++r) {
        float bv = vv[0]; int bi = gi[0];
        #pragma unroll
        for (int j = 1; j < 4; ++j)
            if (vv[j] < bv || (vv[j] == bv && gi[j] < bi)) { bv = vv[j]; bi = gi[j]; }
        #pragma unroll
        for (int off = 32; off > 0; off >>= 1) {
            float ov = __shfl_xor(bv, off, 64);
            int   oi = __shfl_xor(bi, off, 64);
            if (ov < bv || (ov == bv && oi < bi)) { bv = ov; bi = oi; }
        }
        cr_val[r] = bv; cr_idx[r] = bi;
        #pragma unroll
        for (int j = 0; j < 4; ++j) if (gi[j] == bi) vv[j] = INFINITY;
    }
    if (lane == 0) {
        int base = ((b*SL + sl)*NN + w)*NN;
        int* wsi = (int*)ws;
        #pragma unroll
        for (int r = 0; r < NN; ++r) {
            ws[OFF_CVAL + base + r]  = cr_val[r];
            wsi[OFF_CIDX + base + r] = cr_idx[r];
        }
    }
    if (tid == 0)
        ws[OFF_OBJ + b*SL + sl] = obj_s[0] + obj_s[1] + obj_s[2] + obj_s[3];
}

// ------- Kernel B: merge candidates, assign, weighted loss -> one atomicAdd -------
__global__ void __launch_bounds__(THREADS)
crit_match(const float* __restrict__ loc_out, const float* __restrict__ obj_logit,
           const float* __restrict__ cls_logit, const float* __restrict__ gt_loc,
           const float* __restrict__ gt_cls, float* __restrict__ ws,
           float* __restrict__ out)
{
    __shared__ float cand_val[NN][NN];
    __shared__ int   cand_idx[NN][NN];
    __shared__ int   s_pred[NN];
    __shared__ float s_best[4];
    __shared__ int   s_bestc[4];
    __shared__ float red[4];
    __shared__ float s_lo;      // weighted loc+obj contribution

    const int b = blockIdx.x, tid = threadIdx.x;
    const int w = tid >> 6, lane = tid & 63;
    const int* wsi = (const int*)ws;

    // Merge: wave w holds the SL*NN = 32 candidates of row w in lanes 0..31.
    {
        float v = INFINITY; int idx = INT_MAX;
        if (lane < SL*NN) {
            int sl = lane >> 2, r = lane & 3;
            int base = ((b*SL + sl)*NN + w)*NN + r;
            v   = ws[OFF_CVAL + base];
            idx = wsi[OFF_CIDX + base];
        }
        #pragma unroll
        for (int r2 = 0; r2 < NN; ++r2) {
            float bv = v; int bi = idx;
            #pragma unroll
            for (int off = 32; off > 0; off >>= 1) {
                float ov = __shfl_xor(bv, off, 64);
                int   oi = __shfl_xor(bi, off, 64);
                if (ov < bv || (ov == bv && oi < bi)) { bv = ov; bi = oi; }
            }
            if (lane == 0) { cand_val[w][r2] = bv; cand_idx[w][r2] = bi; }
            if (idx == bi) v = INFINITY;   // mask winner
        }
    }
    __syncthreads();

    // Brute force: thread tid evaluates combo tid (a0..a3 = 2-bit fields).
    {
        int a0 = (tid >> 6) & 3, a1 = (tid >> 4) & 3, a2 = (tid >> 2) & 3, a3 = tid & 3;
        int c0 = cand_idx[0][a0], c1 = cand_idx[1][a1];
        int c2 = cand_idx[2][a2], c3 = cand_idx[3][a3];
        bool valid = (c0!=c1) & (c0!=c2) & (c0!=c3) & (c1!=c2) & (c1!=c3) & (c2!=c3);
        float t = cand_val[0][a0] + cand_val[1][a1] + cand_val[2][a2] + cand_val[3][a3];
        float bv = valid ? t : INFINITY;
        int   bc = tid;
        #pragma unroll
        for (int off = 32; off > 0; off >>= 1) {
            float ov = __shfl_xor(bv, off, 64);
            int   oc = __shfl_xor(bc, off, 64);
            if (ov < bv || (ov == bv && oc < bc)) { bv = ov; bc = oc; }
        }
        if (lane == 0) { s_best[w] = bv; s_bestc[w] = bc; }
    }
    __syncthreads();

    if (tid == 0) {
        float bv = s_best[0]; int bc = s_bestc[0];
        for (int i = 1; i < 4; ++i)
            if (s_best[i] < bv || (s_best[i] == bv && s_bestc[i] < bc)) { bv = s_best[i]; bc = s_bestc[i]; }
        int a0 = (bc >> 6) & 3, a1 = (bc >> 4) & 3, a2 = (bc >> 2) & 3, a3 = bc & 3;
        s_pred[0] = cand_idx[0][a0]; s_pred[1] = cand_idx[1][a1];
        s_pred[2] = cand_idx[2][a2]; s_pred[3] = cand_idx[3][a3];
    }
    __syncthreads();

    // ---- loc + obj partials: parallel across lanes of wave 0 ----
    // lanes 0..15 : n = lane>>2, d = lane&3, active when d < DD (12 loc terms)
    // lanes 16..19: matched obj logits (negative)
    // lanes 20..20+SL-1: obj base partials
    if (w == 0) {
        float contrib = 0.f;
        if (lane < 16) {
            int n = lane >> 2, d = lane & 3;
            if (d < DD) {
                float diff = loc_out[((size_t)b*KK + s_pred[n])*DD + d]
                           - gt_loc[(b*NN+n)*DD + d];
                contrib = diff*diff / (float)(BB*NN*DD);
            }
        } else if (lane < 20) {
            contrib = -obj_logit[b*KK + s_pred[lane-16]] / (float)(BB*KK);
        } else if (lane < 20+SL) {
            contrib = ws[OFF_OBJ + b*SL + (lane-20)] / (float)(BB*KK);
        }
        #pragma unroll
        for (int off = 32; off > 0; off >>= 1) contrib += __shfl_xor(contrib, off, 64);
        if (lane == 0) s_lo = contrib;
    }

    // cls partial: 256 threads = 4 rows x 64 classes; accurate focal BCE.
    {
        int n = w, c = lane;
        float zz = cls_logit[((size_t)b*KK + s_pred[n])*CC + c];
        float tgt = gt_cls[(b*NN+n)*CC + c];
        float p  = 1.f / (1.f + expf(-zz));
        float ce = fmaxf(zz, 0.f) - zz*tgt + log1pf(expf(-fabsf(zz)));
        float pt = p*tgt + (1.f-p)*(1.f-tgt);
        float at = 0.25f*tgt + 0.75f*(1.f-tgt);
        float om1 = 1.f - pt;
        float r = at * ce * om1 * om1;
        #pragma unroll
        for (int off = 32; off > 0; off >>= 1) r += __shfl_xor(r, off, 64);
        if (lane == 0) red[n] = r;
    }
    __syncthreads();

    // One relaxed float atomic per block: fully-weighted batch contribution.
    if (tid == 0) {
        float total = s_lo + (red[0] + red[1] + red[2] + red[3]) / (float)(BB*NN*CC);
        atomicAdd(out, total);
    }
}

extern "C" void kernel_launch(void* const* d_in, const int* in_sizes, int n_in,
                              void* d_out, int out_size, void* d_ws, size_t ws_size,
                              hipStream_t stream) {
    const float* loc_out   = (const float*)d_in[0];
    const float* obj_logit = (const float*)d_in[1];
    const float* cls_logit = (const float*)d_in[2];
    const float* gt_loc    = (const float*)d_in[3];
    const float* gt_cls    = (const float*)d_in[4];
    float* ws  = (float*)d_ws;
    float* out = (float*)d_out;

    hipLaunchKernelGGL(crit_cost, dim3(SL, BB), dim3(THREADS), 0, stream,
                       loc_out, obj_logit, cls_logit, gt_loc, gt_cls, ws, out);
    hipLaunchKernelGGL(crit_match, dim3(BB), dim3(THREADS), 0, stream,
                       loc_out, obj_logit, cls_logit, gt_loc, gt_cls, ws, out);
}